// Round 8
// baseline (647.807 us; speedup 1.0000x reference)
//
#include <hip/hip_runtime.h>

typedef float    f32x4  __attribute__((ext_vector_type(4)));
typedef float    f32x16 __attribute__((ext_vector_type(16)));
typedef _Float16 f16x4  __attribute__((ext_vector_type(4)));
typedef _Float16 f16x8  __attribute__((ext_vector_type(8)));

#define N_IMG 50000
#define NPAD  50176       // padded n (zeros beyond 50000) for imgT cols / eh
#define BROWS 256
#define CHW   3072
#define BK    64
#define BM    128
#define BN    128
#define EHS   50176       // padded k stride for eh and imgT rows
#define KCHUNK 3136       // 49*64 split-K chunk for GEMM2 (16*3136 = 50176)
#define NSPLIT 16
#define TROWS 64          // prep slab rows
#define TPITCH 132        // prep transpose tile pitch (f16)

// direct global->LDS (wave-uniform LDS base + lane*16B; per-lane global addr)
__device__ __forceinline__ void glds16(const void* g, void* l) {
    __builtin_amdgcn_global_load_lds(
        (const __attribute__((address_space(1))) void*)g,
        (__attribute__((address_space(3))) void*)l, 16, 0, 0);
}

// ---------------- scalars from t ----------------
__global__ void k_scalars(const float* __restrict__ t, float* __restrict__ sc) {
    if (threadIdx.x == 0) {
        double tv  = (double)t[0];
        double ang = tv * (1.5707963267948966 / 1.008);
        double c   = cos(ang);
        double at  = c;
        double bt2 = 1.0 - c * c;
        sc[0] = (float)at;
        sc[1] = (float)bt2;
        sc[2] = (float)(at / bt2);             // c_cross
        sc[3] = (float)(at * at * 0.5 / bt2);  // c_y2
        sc[4] = (float)(1.0 / bt2);            // inv_bt2
    }
}

// ---------------- x -> f16 ----------------
// -||x||^2 logit term is a per-row constant -> cancelled by row softmax; omitted.
__global__ void k_xprep(const float* __restrict__ x, _Float16* __restrict__ xh) {
    int idx = blockIdx.x * 256 + threadIdx.x;
    f32x4 v = ((const f32x4*)x)[idx];
    f16x4 h;
    h[0] = (_Float16)v[0]; h[1] = (_Float16)v[1];
    h[2] = (_Float16)v[2]; h[3] = (_Float16)v[3];
    ((f16x4*)xh)[idx] = h;
}

// ---------------- img f32 -> imgh [n][d] f16 + imgT [d][NPAD] f16 + y2 ----------------
// 64-row slabs; 24 d-tiles of 128 per block. Conflict-light LDS transpose
// (pitch 132: b64 writes ~2-way, u16 broadcast-pair reads ~2-way). No atomics.
__global__ __launch_bounds__(256) void k_prep(const float* __restrict__ img,
        _Float16* __restrict__ imgh, _Float16* __restrict__ imgT,
        float* __restrict__ y2) {
    __shared__ _Float16 LT[TROWS * TPITCH];   // 16.9 KB
    const int tid = threadIdx.x;
    const int n0 = blockIdx.x * TROWS;
    const int rl   = tid >> 5;           // 0..7
    const int dcol = (tid & 31) * 4;     // 0..124
    const int dT   = tid >> 1;           // 0..127 (transpose-write role)
    const int nhT  = (tid & 1) * 32;     // 0/32
    float y2p[8] = {0.f,0.f,0.f,0.f,0.f,0.f,0.f,0.f};

    for (int dt = 0; dt < CHW / 128; ++dt) {
        const int dbase = dt * 128;
        #pragma unroll
        for (int i = 0; i < 8; i++) {
            int nl = rl + 8 * i;
            int n  = n0 + nl;
            f32x4 v;
            if (n < N_IMG) v = *(const f32x4*)(img + (size_t)n * CHW + dbase + dcol);
            else { v[0] = 0.f; v[1] = 0.f; v[2] = 0.f; v[3] = 0.f; }
            y2p[i] += v[0]*v[0] + v[1]*v[1] + v[2]*v[2] + v[3]*v[3];
            f16x4 h;
            h[0] = (_Float16)v[0]; h[1] = (_Float16)v[1];
            h[2] = (_Float16)v[2]; h[3] = (_Float16)v[3];
            if (n < N_IMG) *(f16x4*)(imgh + (size_t)n * CHW + dbase + dcol) = h;
            *(f16x4*)&LT[nl * TPITCH + dcol] = h;
        }
        __syncthreads();
        #pragma unroll
        for (int g = 0; g < 4; g++) {
            f16x8 w;
            #pragma unroll
            for (int jj = 0; jj < 8; jj++) w[jj] = LT[(nhT + g * 8 + jj) * TPITCH + dT];
            *(f16x8*)(imgT + (size_t)(dbase + dT) * EHS + n0 + nhT + g * 8) = w;
        }
        __syncthreads();
    }
    #pragma unroll
    for (int i = 0; i < 8; i++) {
        float s = y2p[i];
        s += __shfl_xor(s, 1); s += __shfl_xor(s, 2); s += __shfl_xor(s, 4);
        s += __shfl_xor(s, 8); s += __shfl_xor(s, 16);
        int n = n0 + rl + 8 * i;
        if ((tid & 31) == 0 && n < N_IMG) y2[n] = s;
    }
}

// ---------------- GEMM1: logits = c_cross*(xh@imghT) - c_y2*y2 ----------------
// m97 structure (proven R4/R6) + XCD-aware flat decode: 784 = 8 XCD x 98;
// mt-pair of an n-tile lands on one XCD (imgh L2 reuse).
__global__ __launch_bounds__(256, 3) void k_gemm1(
        const _Float16* __restrict__ xh, const _Float16* __restrict__ imgh,
        const float* __restrict__ y2g, const float* __restrict__ sc,
        float* __restrict__ logits) {
    __shared__ _Float16 Alds[BM * BK];   // 16 KB, [row][g^(row&7)] 16B granules
    __shared__ _Float16 Blds[BN * BK];   // 16 KB

    const int tid = threadIdx.x;
    const int wid = tid >> 6, lane = tid & 63;
    const int flat = blockIdx.x;          // 0..783
    const int xcd = flat & 7, loc = flat >> 3;          // loc 0..97
    const int m0 = (loc & 1) * BM;
    const int n0 = (xcd * 49 + (loc >> 1)) * BN;

    const _Float16* gA[4]; const _Float16* gB[4];
    _Float16* lA[4]; _Float16* lB[4];
    #pragma unroll
    for (int j = 0; j < 4; j++) {
        int seg = wid * 4 + j;
        int row = seg * 8 + (lane >> 3);
        int off = (((lane & 7) ^ (row & 7)) << 3);   // f16 elements
        gA[j] = xh + (size_t)(m0 + row) * CHW + off;
        int rb = n0 + row; if (rb > N_IMG - 1) rb = N_IMG - 1;
        gB[j] = imgh + (size_t)rb * CHW + off;
        lA[j] = Alds + seg * 512;
        lB[j] = Blds + seg * 512;
    }

    const int wm = wid >> 1, wn = wid & 1;
    const int rm = wm * 64, cn = wn * 64;
    const int lr = lane & 31, hi = lane >> 5;
    const int xm = (lr & 7) << 4;                    // read-side byte XOR
    const char* Ab = (const char*)Alds;
    const char* Bb = (const char*)Blds;
    const int ar0 = (rm + lr) * 128,      ar1 = (rm + 32 + lr) * 128;
    const int br0 = (cn + lr) * 128,      br1 = (cn + 32 + lr) * 128;
    const int kof = hi * 16;

    f32x16 acc[2][2];
    #pragma unroll
    for (int mi = 0; mi < 2; mi++)
        #pragma unroll
        for (int ni = 0; ni < 2; ni++)
            #pragma unroll
            for (int r = 0; r < 16; r++) acc[mi][ni][r] = 0.f;

    for (int it = 0; it < CHW / BK; ++it) {
        if (it) __syncthreads();
        #pragma unroll
        for (int j = 0; j < 4; j++) glds16(gA[j] + it * BK, lA[j]);
        #pragma unroll
        for (int j = 0; j < 4; j++) glds16(gB[j] + it * BK, lB[j]);
        __syncthreads();
        #pragma unroll
        for (int ks = 0; ks < 4; ++ks) {
            int off = (ks * 32 + kof) ^ xm;
            f16x8 a0 = *(const f16x8*)(Ab + ar0 + off);
            f16x8 a1 = *(const f16x8*)(Ab + ar1 + off);
            f16x8 b0 = *(const f16x8*)(Bb + br0 + off);
            f16x8 b1 = *(const f16x8*)(Bb + br1 + off);
            acc[0][0] = __builtin_amdgcn_mfma_f32_32x32x16_f16(a0, b0, acc[0][0], 0, 0, 0);
            acc[0][1] = __builtin_amdgcn_mfma_f32_32x32x16_f16(a0, b1, acc[0][1], 0, 0, 0);
            acc[1][0] = __builtin_amdgcn_mfma_f32_32x32x16_f16(a1, b0, acc[1][0], 0, 0, 0);
            acc[1][1] = __builtin_amdgcn_mfma_f32_32x32x16_f16(a1, b1, acc[1][1], 0, 0, 0);
        }
    }

    const float c_cross = sc[2], c_y2 = sc[3];
    #pragma unroll
    for (int mi = 0; mi < 2; mi++)
        #pragma unroll
        for (int ni = 0; ni < 2; ni++) {
            int col = n0 + cn + ni * 32 + lr;
            if (col >= N_IMG) continue;
            float y2v = y2g[col];
            f32x16 v = acc[mi][ni];
            #pragma unroll
            for (int r = 0; r < 16; r++) {
                int row = m0 + rm + mi * 32 + (r & 3) + 8 * (r >> 2) + 4 * hi;
                logits[(size_t)row * N_IMG + col] = c_cross * v[r] - c_y2 * y2v;
            }
        }
}

// ---------------- fused row max + exp + row sum (writes padded eh) ----------------
__global__ void k_softmax(const float* __restrict__ logits, _Float16* __restrict__ eh,
                          float* __restrict__ rowsum) {
    int row = blockIdx.x, tid = threadIdx.x;
    const f32x4* lr = (const f32x4*)(logits + (size_t)row * N_IMG);
    _Float16* erow = eh + (size_t)row * EHS;
    f16x4* er = (f16x4*)erow;
    __shared__ float wred[4];

    if (tid < EHS - N_IMG) erow[N_IMG + tid] = (_Float16)0.f;   // zero K-tail pad

    float m = -3.0e38f;
    for (int i = tid; i < N_IMG / 4; i += 256) {
        f32x4 v = lr[i];
        m = fmaxf(m, fmaxf(fmaxf(v[0], v[1]), fmaxf(v[2], v[3])));
    }
    for (int o = 32; o > 0; o >>= 1) m = fmaxf(m, __shfl_down(m, o));
    if ((tid & 63) == 0) wred[tid >> 6] = m;
    __syncthreads();
    m = fmaxf(fmaxf(wred[0], wred[1]), fmaxf(wred[2], wred[3]));
    __syncthreads();

    float s = 0.f;
    for (int i = tid; i < N_IMG / 4; i += 256) {
        f32x4 v = lr[i];
        float e0 = __expf(v[0] - m), e1 = __expf(v[1] - m);
        float e2 = __expf(v[2] - m), e3 = __expf(v[3] - m);
        s += (e0 + e1) + (e2 + e3);
        f16x4 h;
        h[0] = (_Float16)e0; h[1] = (_Float16)e1;
        h[2] = (_Float16)e2; h[3] = (_Float16)e3;
        er[i] = h;
    }
    for (int o = 32; o > 0; o >>= 1) s += __shfl_down(s, o);
    if ((tid & 63) == 0) wred[tid >> 6] = s;
    __syncthreads();
    if (tid == 0) rowsum[row] = (wred[0] + wred[1]) + (wred[2] + wred[3]);
}

// ---------------- GEMM2: partial[ck] = eh[:,chunk] @ imgT^T[chunk,:] ----------------
// All-glds (proven R6) + XCD-aware flat decode: 768 = 8 XCD x 96; each split-K
// chunk pinned to one XCD (its 19.3 MB imgT slice reused via that XCD's L2).
__global__ __launch_bounds__(256, 3) void k_gemm2(
        const _Float16* __restrict__ eh, const _Float16* __restrict__ imgT,
        float* __restrict__ partial) {
    __shared__ _Float16 Alds[BM * BK];   // 16 KB
    __shared__ _Float16 Blds[BN * BK];   // 16 KB

    const int tid = threadIdx.x;
    const int wid = tid >> 6, lane = tid & 63;
    const int flat = blockIdx.x;          // 0..767
    const int xcd = flat & 7, loc = flat >> 3;          // loc 0..95
    const int ck  = xcd * 2 + (loc >= 48 ? 1 : 0);
    const int rem = loc - (loc >= 48 ? 48 : 0);         // 0..47
    const int m0 = (rem & 1) * BM;
    const int d0 = (rem >> 1) * BN;
    const int kbase = ck * KCHUNK;

    const _Float16* gA[4]; const _Float16* gB[4];
    _Float16* lA[4]; _Float16* lB[4];
    #pragma unroll
    for (int j = 0; j < 4; j++) {
        int seg = wid * 4 + j;
        int row = seg * 8 + (lane >> 3);
        int off = (((lane & 7) ^ (row & 7)) << 3);
        gA[j] = eh   + (size_t)(m0 + row) * EHS + kbase + off;
        gB[j] = imgT + (size_t)(d0 + row) * EHS + kbase + off;
        lA[j] = Alds + seg * 512;
        lB[j] = Blds + seg * 512;
    }

    const int wm = wid >> 1, wn = wid & 1;
    const int rm = wm * 64, cn = wn * 64;
    const int lr = lane & 31, hi = lane >> 5;
    const int xm = (lr & 7) << 4;
    const char* Ab = (const char*)Alds;
    const char* Bb = (const char*)Blds;
    const int ar0 = (rm + lr) * 128,      ar1 = (rm + 32 + lr) * 128;
    const int br0 = (cn + lr) * 128,      br1 = (cn + 32 + lr) * 128;
    const int kof = hi * 16;

    f32x16 acc[2][2];
    #pragma unroll
    for (int mi = 0; mi < 2; mi++)
        #pragma unroll
        for (int ni = 0; ni < 2; ni++)
            #pragma unroll
            for (int r = 0; r < 16; r++) acc[mi][ni][r] = 0.f;

    for (int it = 0; it < KCHUNK / BK; ++it) {
        if (it) __syncthreads();
        #pragma unroll
        for (int j = 0; j < 4; j++) glds16(gA[j] + it * BK, lA[j]);
        #pragma unroll
        for (int j = 0; j < 4; j++) glds16(gB[j] + it * BK, lB[j]);
        __syncthreads();
        #pragma unroll
        for (int ks = 0; ks < 4; ++ks) {
            int off = (ks * 32 + kof) ^ xm;
            f16x8 a0 = *(const f16x8*)(Ab + ar0 + off);
            f16x8 a1 = *(const f16x8*)(Ab + ar1 + off);
            f16x8 b0 = *(const f16x8*)(Bb + br0 + off);
            f16x8 b1 = *(const f16x8*)(Bb + br1 + off);
            acc[0][0] = __builtin_amdgcn_mfma_f32_32x32x16_f16(a0, b0, acc[0][0], 0, 0, 0);
            acc[0][1] = __builtin_amdgcn_mfma_f32_32x32x16_f16(a0, b1, acc[0][1], 0, 0, 0);
            acc[1][0] = __builtin_amdgcn_mfma_f32_32x32x16_f16(a1, b0, acc[1][0], 0, 0, 0);
            acc[1][1] = __builtin_amdgcn_mfma_f32_32x32x16_f16(a1, b1, acc[1][1], 0, 0, 0);
        }
    }

    float* pp = partial + (size_t)ck * BROWS * CHW;
    #pragma unroll
    for (int mi = 0; mi < 2; mi++)
        #pragma unroll
        for (int ni = 0; ni < 2; ni++) {
            int dcol = d0 + cn + ni * 32 + lr;
            f32x16 v = acc[mi][ni];
            #pragma unroll
            for (int r = 0; r < 16; r++) {
                int row = m0 + rm + mi * 32 + (r & 3) + 8 * (r >> 2) + 4 * hi;
                pp[(size_t)row * CHW + dcol] = v[r];
            }
        }
}

// ---------------- reduce partials + final score ----------------
__global__ void k_final(const float* __restrict__ partial, const float* __restrict__ x,
                        const float* __restrict__ rowsum, const float* __restrict__ sc,
                        float* __restrict__ out) {
    int idx = blockIdx.x * 256 + threadIdx.x;
    int row = idx / (CHW / 4);
    float at = sc[0], invbt2 = sc[4];
    float scale = at * invbt2 / rowsum[row];
    const f32x4* p4 = (const f32x4*)partial;
    f32x4 s = p4[idx];
    #pragma unroll
    for (int c = 1; c < NSPLIT; c++) s = s + p4[(size_t)c * (BROWS * CHW / 4) + idx];
    f32x4 xv = ((const f32x4*)x)[idx];
    f32x4 o;
    #pragma unroll
    for (int j = 0; j < 4; j++) o[j] = s[j] * scale - xv[j] * invbt2;
    ((f32x4*)out)[idx] = o;
}

extern "C" void kernel_launch(void* const* d_in, const int* in_sizes, int n_in,
                              void* d_out, int out_size, void* d_ws, size_t ws_size,
                              hipStream_t stream) {
    const float* t   = (const float*)d_in[0];
    const float* x   = (const float*)d_in[1];
    const float* img = (const float*)d_in[2];
    float* out = (float*)d_out;
    char* ws = (char*)d_ws;

    // ws layout (bytes)
    float*    sc     = (float*)(ws + 0);                   // 64 B
    float*    rowsum = (float*)(ws + 256);                 // 1 KB
    float*    y2     = (float*)(ws + 4096);                // 200 KB
    _Float16* xh     = (_Float16*)(ws + 212992);           // 1.5 MB
    _Float16* imgh   = (_Float16*)(ws + 2097152);          // 307.2 MB [N_IMG][CHW]
    _Float16* imgT   = (_Float16*)(ws + 309297152);        // 308.3 MB [CHW][EHS]
    _Float16* eh     = (_Float16*)(ws + 617578496);        // 25.7 MB  [b][EHS]
    float*    logits = (float*)(ws + 643268608);           // 51.2 MB
    float*    partial = logits;                            // reused (50.4 MB)

    k_scalars<<<1, 64, 0, stream>>>(t, sc);
    k_xprep<<<(BROWS * CHW / 4) / 256, 256, 0, stream>>>(x, xh);
    k_prep<<<NPAD / TROWS, 256, 0, stream>>>(img, imgh, imgT, y2);
    k_gemm1<<<784, 256, 0, stream>>>(xh, imgh, y2, sc, logits);
    k_softmax<<<256, 256, 0, stream>>>(logits, eh, rowsum);
    k_gemm2<<<768, 256, 0, stream>>>(eh, imgT, partial);
    k_final<<<(BROWS * CHW / 4) / 256, 256, 0, stream>>>(partial, x, rowsum, sc, out);
}

// Round 9
// 524.466 us; speedup vs baseline: 1.2352x; 1.2352x over previous
//
#include <hip/hip_runtime.h>

typedef float    f32x4  __attribute__((ext_vector_type(4)));
typedef float    f32x16 __attribute__((ext_vector_type(16)));
typedef _Float16 f16x4  __attribute__((ext_vector_type(4)));
typedef _Float16 f16x8  __attribute__((ext_vector_type(8)));

#define N_IMG 50000
#define NPAD  50176       // imgh padded rows (zeros beyond 50000)
#define BROWS 256
#define CHW   3072
#define BK    64
#define BM    128
#define BN    128
#define EHS   50176       // padded k stride for eh (zeros beyond 50000)
#define KCHUNK 3136       // 49*64 split-K chunk for GEMM2 (16*3136 = 50176)
#define NSPLIT 16

// direct global->LDS (wave-uniform LDS base + lane*16B; per-lane global addr)
__device__ __forceinline__ void glds16(const void* g, void* l) {
    __builtin_amdgcn_global_load_lds(
        (const __attribute__((address_space(1))) void*)g,
        (__attribute__((address_space(3))) void*)l, 16, 0, 0);
}

// ---------------- scalars from t ----------------
__global__ void k_scalars(const float* __restrict__ t, float* __restrict__ sc) {
    if (threadIdx.x == 0) {
        double tv  = (double)t[0];
        double ang = tv * (1.5707963267948966 / 1.008);
        double c   = cos(ang);
        double at  = c;
        double bt2 = 1.0 - c * c;
        sc[0] = (float)at;
        sc[1] = (float)bt2;
        sc[2] = (float)(at / bt2);             // c_cross
        sc[3] = (float)(at * at * 0.5 / bt2);  // c_y2
        sc[4] = (float)(1.0 / bt2);            // inv_bt2
    }
}

// ---------------- x -> f16 ----------------
// -||x||^2 logit term is a per-row constant -> cancelled by row softmax; omitted.
__global__ void k_xprep(const float* __restrict__ x, _Float16* __restrict__ xh) {
    int idx = blockIdx.x * 256 + threadIdx.x;
    f32x4 v = ((const f32x4*)x)[idx];
    f16x4 h;
    h[0] = (_Float16)v[0]; h[1] = (_Float16)v[1];
    h[2] = (_Float16)v[2]; h[3] = (_Float16)v[3];
    ((f16x4*)xh)[idx] = h;
}

// ---------------- img -> f16 [n][d] + y2 (row per block; R4-proven ~150us) ----------
// Rows >= N_IMG written as zeros (NaN-safe padding for GEMM2's K tail).
__global__ void k_prep(const float* __restrict__ img, _Float16* __restrict__ imgh,
                       float* __restrict__ y2) {
    int row = blockIdx.x, tid = threadIdx.x;
    f16x4* dst = (f16x4*)(imgh + (size_t)row * CHW);
    if (row >= N_IMG) {
        f16x4 z = {(_Float16)0.f, (_Float16)0.f, (_Float16)0.f, (_Float16)0.f};
        #pragma unroll
        for (int i = 0; i < 3; i++) dst[tid + i * 256] = z;
        return;
    }
    const f32x4* src = (const f32x4*)(img + (size_t)row * CHW);
    float s = 0.f;
    #pragma unroll
    for (int i = 0; i < 3; i++) {
        f32x4 v = src[tid + i * 256];
        s += v[0]*v[0] + v[1]*v[1] + v[2]*v[2] + v[3]*v[3];
        f16x4 h;
        h[0] = (_Float16)v[0]; h[1] = (_Float16)v[1];
        h[2] = (_Float16)v[2]; h[3] = (_Float16)v[3];
        dst[tid + i * 256] = h;
    }
    for (int o = 32; o > 0; o >>= 1) s += __shfl_down(s, o);
    __shared__ float wsum[4];
    if ((tid & 63) == 0) wsum[tid >> 6] = s;
    __syncthreads();
    if (tid == 0) y2[row] = (wsum[0] + wsum[1]) + (wsum[2] + wsum[3]);
}

// ---------------- GEMM1: logits = c_cross*(xh@imghT) - c_y2*y2 ----------------
// m97 structure (proven R4/R6/R8) + XCD-aware flat decode (784 = 8 x 98).
__global__ __launch_bounds__(256, 3) void k_gemm1(
        const _Float16* __restrict__ xh, const _Float16* __restrict__ imgh,
        const float* __restrict__ y2g, const float* __restrict__ sc,
        float* __restrict__ logits) {
    __shared__ _Float16 Alds[BM * BK];   // 16 KB, [row][g^(row&7)] 16B granules
    __shared__ _Float16 Blds[BN * BK];   // 16 KB

    const int tid = threadIdx.x;
    const int wid = tid >> 6, lane = tid & 63;
    const int flat = blockIdx.x;          // 0..783
    const int xcd = flat & 7, loc = flat >> 3;          // loc 0..97
    const int m0 = (loc & 1) * BM;
    const int n0 = (xcd * 49 + (loc >> 1)) * BN;

    const _Float16* gA[4]; const _Float16* gB[4];
    _Float16* lA[4]; _Float16* lB[4];
    #pragma unroll
    for (int j = 0; j < 4; j++) {
        int seg = wid * 4 + j;
        int row = seg * 8 + (lane >> 3);
        int off = (((lane & 7) ^ (row & 7)) << 3);   // f16 elements
        gA[j] = xh + (size_t)(m0 + row) * CHW + off;
        int rb = n0 + row; if (rb > N_IMG - 1) rb = N_IMG - 1;
        gB[j] = imgh + (size_t)rb * CHW + off;
        lA[j] = Alds + seg * 512;
        lB[j] = Blds + seg * 512;
    }

    const int wm = wid >> 1, wn = wid & 1;
    const int rm = wm * 64, cn = wn * 64;
    const int lr = lane & 31, hi = lane >> 5;
    const int xm = (lr & 7) << 4;                    // read-side byte XOR
    const char* Ab = (const char*)Alds;
    const char* Bb = (const char*)Blds;
    const int ar0 = (rm + lr) * 128,      ar1 = (rm + 32 + lr) * 128;
    const int br0 = (cn + lr) * 128,      br1 = (cn + 32 + lr) * 128;
    const int kof = hi * 16;

    f32x16 acc[2][2];
    #pragma unroll
    for (int mi = 0; mi < 2; mi++)
        #pragma unroll
        for (int ni = 0; ni < 2; ni++)
            #pragma unroll
            for (int r = 0; r < 16; r++) acc[mi][ni][r] = 0.f;

    for (int it = 0; it < CHW / BK; ++it) {
        if (it) __syncthreads();
        #pragma unroll
        for (int j = 0; j < 4; j++) glds16(gA[j] + it * BK, lA[j]);
        #pragma unroll
        for (int j = 0; j < 4; j++) glds16(gB[j] + it * BK, lB[j]);
        __syncthreads();
        #pragma unroll
        for (int ks = 0; ks < 4; ++ks) {
            int off = (ks * 32 + kof) ^ xm;
            f16x8 a0 = *(const f16x8*)(Ab + ar0 + off);
            f16x8 a1 = *(const f16x8*)(Ab + ar1 + off);
            f16x8 b0 = *(const f16x8*)(Bb + br0 + off);
            f16x8 b1 = *(const f16x8*)(Bb + br1 + off);
            acc[0][0] = __builtin_amdgcn_mfma_f32_32x32x16_f16(a0, b0, acc[0][0], 0, 0, 0);
            acc[0][1] = __builtin_amdgcn_mfma_f32_32x32x16_f16(a0, b1, acc[0][1], 0, 0, 0);
            acc[1][0] = __builtin_amdgcn_mfma_f32_32x32x16_f16(a1, b0, acc[1][0], 0, 0, 0);
            acc[1][1] = __builtin_amdgcn_mfma_f32_32x32x16_f16(a1, b1, acc[1][1], 0, 0, 0);
        }
    }

    const float c_cross = sc[2], c_y2 = sc[3];
    #pragma unroll
    for (int mi = 0; mi < 2; mi++)
        #pragma unroll
        for (int ni = 0; ni < 2; ni++) {
            int col = n0 + cn + ni * 32 + lr;
            if (col >= N_IMG) continue;
            float y2v = y2g[col];
            f32x16 v = acc[mi][ni];
            #pragma unroll
            for (int r = 0; r < 16; r++) {
                int row = m0 + rm + mi * 32 + (r & 3) + 8 * (r >> 2) + 4 * hi;
                logits[(size_t)row * N_IMG + col] = c_cross * v[r] - c_y2 * y2v;
            }
        }
}

// ---------------- fused row max + exp + row sum (writes padded eh) ----------------
__global__ void k_softmax(const float* __restrict__ logits, _Float16* __restrict__ eh,
                          float* __restrict__ rowsum) {
    int row = blockIdx.x, tid = threadIdx.x;
    const f32x4* lr = (const f32x4*)(logits + (size_t)row * N_IMG);
    _Float16* erow = eh + (size_t)row * EHS;
    f16x4* er = (f16x4*)erow;
    __shared__ float wred[4];

    if (tid < EHS - N_IMG) erow[N_IMG + tid] = (_Float16)0.f;   // zero K-tail pad

    float m = -3.0e38f;
    for (int i = tid; i < N_IMG / 4; i += 256) {
        f32x4 v = lr[i];
        m = fmaxf(m, fmaxf(fmaxf(v[0], v[1]), fmaxf(v[2], v[3])));
    }
    for (int o = 32; o > 0; o >>= 1) m = fmaxf(m, __shfl_down(m, o));
    if ((tid & 63) == 0) wred[tid >> 6] = m;
    __syncthreads();
    m = fmaxf(fmaxf(wred[0], wred[1]), fmaxf(wred[2], wred[3]));
    __syncthreads();

    float s = 0.f;
    for (int i = tid; i < N_IMG / 4; i += 256) {
        f32x4 v = lr[i];
        float e0 = __expf(v[0] - m), e1 = __expf(v[1] - m);
        float e2 = __expf(v[2] - m), e3 = __expf(v[3] - m);
        s += (e0 + e1) + (e2 + e3);
        f16x4 h;
        h[0] = (_Float16)e0; h[1] = (_Float16)e1;
        h[2] = (_Float16)e2; h[3] = (_Float16)e3;
        er[i] = h;
    }
    for (int o = 32; o > 0; o >>= 1) s += __shfl_down(s, o);
    if ((tid & 63) == 0) wred[tid >> 6] = s;
    __syncthreads();
    if (tid == 0) rowsum[row] = (wred[0] + wred[1]) + (wred[2] + wred[3]);
}

// ---------------- GEMM2: partial[ck] = eh[:,chunk] @ imgh[chunk,:] ----------------
// Fused in-LDS transpose: imgh k-rows glds16 -> Tmp[64k][128d] f16 (linear),
// per-iter LDS transpose Tmp -> Blds[d][k] (swizzled, matches m97 reader),
// A (eh) glds + swizzle, double-buffered. 3-phase loop, 64 KB LDS, 2 blk/CU.
__global__ __launch_bounds__(256, 2) void k_gemm2(
        const _Float16* __restrict__ eh, const _Float16* __restrict__ imgh,
        float* __restrict__ partial) {
    __shared__ _Float16 Alds[2][BM * BK];  // 2 x 16 KB
    __shared__ _Float16 Blds[BN * BK];     // 16 KB, [d][k] swizzled granules
    __shared__ _Float16 Tmp[BK * BN];      // 16 KB, [k][d] linear

    const int tid = threadIdx.x;
    const int wid = tid >> 6, lane = tid & 63;
    const int flat = blockIdx.x;          // 0..767
    const int xcd = flat & 7, loc = flat >> 3;          // loc 0..95
    const int ck  = xcd * 2 + (loc >= 48 ? 1 : 0);
    const int rem = loc - (loc >= 48 ? 48 : 0);         // 0..47
    const int m0 = (rem & 1) * BM;
    const int d0 = (rem >> 1) * BN;
    const int kbase = ck * KCHUNK;

    const _Float16* gA[4]; int lAo[4];
    const _Float16* gB[4]; _Float16* lB[4];
    #pragma unroll
    for (int j = 0; j < 4; j++) {
        int seg = wid * 4 + j;                         // 0..15
        // A: rows seg*8..+8 of eh, swizzled granules
        int row = seg * 8 + (lane >> 3);
        int off = (((lane & 7) ^ (row & 7)) << 3);
        gA[j] = eh + (size_t)(m0 + row) * EHS + kbase + off;
        lAo[j] = seg * 512;
        // B: issue covers 4 imgh k-rows (256B each): lane -> (k-row, 16B granule)
        gB[j] = imgh + (size_t)(kbase + seg * 4 + (lane >> 4)) * CHW + d0 + (lane & 15) * 8;
        lB[j] = Tmp + seg * 512;
    }

    const int wm = wid >> 1, wn = wid & 1;
    const int rm = wm * 64, cn = wn * 64;
    const int lr = lane & 31, hi = lane >> 5;
    const int xm = (lr & 7) << 4;
    const int ar0 = (rm + lr) * 128, ar1 = (rm + 32 + lr) * 128;
    const int br0 = (cn + lr) * 128, br1 = (cn + 32 + lr) * 128;
    const int kof = hi * 16;

    f32x16 acc[2][2];
    #pragma unroll
    for (int mi = 0; mi < 2; mi++)
        #pragma unroll
        for (int ni = 0; ni < 2; ni++)
            #pragma unroll
            for (int r = 0; r < 16; r++) acc[mi][ni][r] = 0.f;

    // prologue: stage it=0
    #pragma unroll
    for (int j = 0; j < 4; j++) glds16(gA[j], (_Float16*)Alds[0] + lAo[j]);
    #pragma unroll
    for (int j = 0; j < 4; j++) glds16(gB[j], lB[j]);

    int c = 0;
    for (int it = 0; it < KCHUNK / BK; ++it) {
        __syncthreads();   // glds(it) landed; MFMA(it-1) reads done
        // transpose Tmp[k][d] -> Blds[d][k-swizzled]; banks: reads 2-way, writes spread
        #pragma unroll
        for (int tt = 0; tt < 4; tt++) {
            int gid = tid + tt * 256;
            int d = gid & 127, oct = gid >> 7;         // oct = k-octet 0..7
            f16x8 w;
            #pragma unroll
            for (int j = 0; j < 8; j++) w[j] = Tmp[(oct * 8 + j) * 128 + d];
            *(f16x8*)((char*)Blds + d * 128 + ((oct ^ (d & 7)) << 4)) = w;
        }
        __syncthreads();   // transpose done; Tmp free; Blds ready
        if (it + 1 < KCHUNK / BK) {                    // prefetch overlaps MFMA
            #pragma unroll
            for (int j = 0; j < 4; j++)
                glds16(gA[j] + (it + 1) * BK, (_Float16*)Alds[c ^ 1] + lAo[j]);
            #pragma unroll
            for (int j = 0; j < 4; j++)
                glds16(gB[j] + (size_t)(it + 1) * BK * CHW, lB[j]);
        }
        const char* Ab = (const char*)Alds[c];
        const char* Bb = (const char*)Blds;
        #pragma unroll
        for (int ks = 0; ks < 4; ++ks) {
            int off = (ks * 32 + kof) ^ xm;
            f16x8 a0 = *(const f16x8*)(Ab + ar0 + off);
            f16x8 a1 = *(const f16x8*)(Ab + ar1 + off);
            f16x8 b0 = *(const f16x8*)(Bb + br0 + off);
            f16x8 b1 = *(const f16x8*)(Bb + br1 + off);
            acc[0][0] = __builtin_amdgcn_mfma_f32_32x32x16_f16(a0, b0, acc[0][0], 0, 0, 0);
            acc[0][1] = __builtin_amdgcn_mfma_f32_32x32x16_f16(a0, b1, acc[0][1], 0, 0, 0);
            acc[1][0] = __builtin_amdgcn_mfma_f32_32x32x16_f16(a1, b0, acc[1][0], 0, 0, 0);
            acc[1][1] = __builtin_amdgcn_mfma_f32_32x32x16_f16(a1, b1, acc[1][1], 0, 0, 0);
        }
        c ^= 1;
    }

    float* pp = partial + (size_t)ck * BROWS * CHW;
    #pragma unroll
    for (int mi = 0; mi < 2; mi++)
        #pragma unroll
        for (int ni = 0; ni < 2; ni++) {
            int dcol = d0 + cn + ni * 32 + lr;
            f32x16 v = acc[mi][ni];
            #pragma unroll
            for (int r = 0; r < 16; r++) {
                int row = m0 + rm + mi * 32 + (r & 3) + 8 * (r >> 2) + 4 * hi;
                pp[(size_t)row * CHW + dcol] = v[r];
            }
        }
}

// ---------------- reduce partials + final score ----------------
__global__ void k_final(const float* __restrict__ partial, const float* __restrict__ x,
                        const float* __restrict__ rowsum, const float* __restrict__ sc,
                        float* __restrict__ out) {
    int idx = blockIdx.x * 256 + threadIdx.x;
    int row = idx / (CHW / 4);
    float at = sc[0], invbt2 = sc[4];
    float scale = at * invbt2 / rowsum[row];
    const f32x4* p4 = (const f32x4*)partial;
    f32x4 s = p4[idx];
    #pragma unroll
    for (int c = 1; c < NSPLIT; c++) s = s + p4[(size_t)c * (BROWS * CHW / 4) + idx];
    f32x4 xv = ((const f32x4*)x)[idx];
    f32x4 o;
    #pragma unroll
    for (int j = 0; j < 4; j++) o[j] = s[j] * scale - xv[j] * invbt2;
    ((f32x4*)out)[idx] = o;
}

extern "C" void kernel_launch(void* const* d_in, const int* in_sizes, int n_in,
                              void* d_out, int out_size, void* d_ws, size_t ws_size,
                              hipStream_t stream) {
    const float* t   = (const float*)d_in[0];
    const float* x   = (const float*)d_in[1];
    const float* img = (const float*)d_in[2];
    float* out = (float*)d_out;
    char* ws = (char*)d_ws;

    // ws layout (bytes)
    float*    sc     = (float*)(ws + 0);                   // 64 B
    float*    rowsum = (float*)(ws + 256);                 // 1 KB
    float*    y2     = (float*)(ws + 4096);                // 200 KB
    _Float16* xh     = (_Float16*)(ws + 212992);           // 1.5 MB
    _Float16* imgh   = (_Float16*)(ws + 2097152);          // 308.3 MB [NPAD][CHW]
    _Float16* eh     = (_Float16*)(ws + 310378496);        // 25.7 MB  [b][EHS]
    float*    logits = (float*)(ws + 336068608);           // 51.2 MB
    float*    partial = logits;                            // reused (50.4 MB)

    k_scalars<<<1, 64, 0, stream>>>(t, sc);
    k_xprep<<<(BROWS * CHW / 4) / 256, 256, 0, stream>>>(x, xh);
    k_prep<<<NPAD, 256, 0, stream>>>(img, imgh, y2);
    k_gemm1<<<784, 256, 0, stream>>>(xh, imgh, y2, sc, logits);
    k_softmax<<<256, 256, 0, stream>>>(logits, eh, rowsum);
    k_gemm2<<<768, 256, 0, stream>>>(eh, imgh, partial);
    k_final<<<(BROWS * CHW / 4) / 256, 256, 0, stream>>>(partial, x, rowsum, sc, out);
}

// Round 10
// 481.534 us; speedup vs baseline: 1.3453x; 1.0892x over previous
//
#include <hip/hip_runtime.h>

typedef float    f32x4  __attribute__((ext_vector_type(4)));
typedef float    f32x16 __attribute__((ext_vector_type(16)));
typedef _Float16 f16x4  __attribute__((ext_vector_type(4)));
typedef _Float16 f16x8  __attribute__((ext_vector_type(8)));

#define N_IMG 50000
#define NPAD  50176       // imgh padded rows (zeros beyond 50000)
#define BROWS 256
#define CHW   3072
#define BK    64
#define BM    128
#define BN    128
#define EHS   50176       // padded k stride for eh (zeros beyond 50000)
#define KCHUNK 3136       // 49*64 split-K chunk for GEMM2 (16*3136 = 50176)
#define NSPLIT 16

// direct global->LDS (wave-uniform LDS base + lane*16B; per-lane global addr)
__device__ __forceinline__ void glds16(const void* g, void* l) {
    __builtin_amdgcn_global_load_lds(
        (const __attribute__((address_space(1))) void*)g,
        (__attribute__((address_space(3))) void*)l, 16, 0, 0);
}

// ---------------- scalars from t ----------------
__global__ void k_scalars(const float* __restrict__ t, float* __restrict__ sc) {
    if (threadIdx.x == 0) {
        double tv  = (double)t[0];
        double ang = tv * (1.5707963267948966 / 1.008);
        double c   = cos(ang);
        double at  = c;
        double bt2 = 1.0 - c * c;
        sc[0] = (float)at;
        sc[1] = (float)bt2;
        sc[2] = (float)(at / bt2);             // c_cross
        sc[3] = (float)(at * at * 0.5 / bt2);  // c_y2
        sc[4] = (float)(1.0 / bt2);            // inv_bt2
    }
}

// ---------------- x -> f16 ----------------
// -||x||^2 logit term is a per-row constant -> cancelled by row softmax; omitted.
__global__ void k_xprep(const float* __restrict__ x, _Float16* __restrict__ xh) {
    int idx = blockIdx.x * 256 + threadIdx.x;
    f32x4 v = ((const f32x4*)x)[idx];
    f16x4 h;
    h[0] = (_Float16)v[0]; h[1] = (_Float16)v[1];
    h[2] = (_Float16)v[2]; h[3] = (_Float16)v[3];
    ((f16x4*)xh)[idx] = h;
}

// ---------------- img -> f16 [n][d] + y2 (row per block; proven ~150us) ----------
// Rows >= N_IMG written as zeros (NaN-safe padding for GEMM2's K tail).
__global__ void k_prep(const float* __restrict__ img, _Float16* __restrict__ imgh,
                       float* __restrict__ y2) {
    int row = blockIdx.x, tid = threadIdx.x;
    f16x4* dst = (f16x4*)(imgh + (size_t)row * CHW);
    if (row >= N_IMG) {
        f16x4 z = {(_Float16)0.f, (_Float16)0.f, (_Float16)0.f, (_Float16)0.f};
        #pragma unroll
        for (int i = 0; i < 3; i++) dst[tid + i * 256] = z;
        return;
    }
    const f32x4* src = (const f32x4*)(img + (size_t)row * CHW);
    float s = 0.f;
    #pragma unroll
    for (int i = 0; i < 3; i++) {
        f32x4 v = src[tid + i * 256];
        s += v[0]*v[0] + v[1]*v[1] + v[2]*v[2] + v[3]*v[3];
        f16x4 h;
        h[0] = (_Float16)v[0]; h[1] = (_Float16)v[1];
        h[2] = (_Float16)v[2]; h[3] = (_Float16)v[3];
        dst[tid + i * 256] = h;
    }
    for (int o = 32; o > 0; o >>= 1) s += __shfl_down(s, o);
    __shared__ float wsum[4];
    if ((tid & 63) == 0) wsum[tid >> 6] = s;
    __syncthreads();
    if (tid == 0) y2[row] = (wsum[0] + wsum[1]) + (wsum[2] + wsum[3]);
}

// ---------------- GEMM1: logits = c_cross*(xh@imghT) - c_y2*y2 ----------------
// m97 structure (proven R4/R6/R8/R9) + XCD-aware flat decode (784 = 8 x 98).
__global__ __launch_bounds__(256, 3) void k_gemm1(
        const _Float16* __restrict__ xh, const _Float16* __restrict__ imgh,
        const float* __restrict__ y2g, const float* __restrict__ sc,
        float* __restrict__ logits) {
    __shared__ _Float16 Alds[BM * BK];   // 16 KB, [row][g^(row&7)] 16B granules
    __shared__ _Float16 Blds[BN * BK];   // 16 KB

    const int tid = threadIdx.x;
    const int wid = tid >> 6, lane = tid & 63;
    const int flat = blockIdx.x;          // 0..783
    const int xcd = flat & 7, loc = flat >> 3;          // loc 0..97
    const int m0 = (loc & 1) * BM;
    const int n0 = (xcd * 49 + (loc >> 1)) * BN;

    const _Float16* gA[4]; const _Float16* gB[4];
    _Float16* lA[4]; _Float16* lB[4];
    #pragma unroll
    for (int j = 0; j < 4; j++) {
        int seg = wid * 4 + j;
        int row = seg * 8 + (lane >> 3);
        int off = (((lane & 7) ^ (row & 7)) << 3);   // f16 elements
        gA[j] = xh + (size_t)(m0 + row) * CHW + off;
        int rb = n0 + row; if (rb > N_IMG - 1) rb = N_IMG - 1;
        gB[j] = imgh + (size_t)rb * CHW + off;
        lA[j] = Alds + seg * 512;
        lB[j] = Blds + seg * 512;
    }

    const int wm = wid >> 1, wn = wid & 1;
    const int rm = wm * 64, cn = wn * 64;
    const int lr = lane & 31, hi = lane >> 5;
    const int xm = (lr & 7) << 4;                    // read-side byte XOR
    const char* Ab = (const char*)Alds;
    const char* Bb = (const char*)Blds;
    const int ar0 = (rm + lr) * 128,      ar1 = (rm + 32 + lr) * 128;
    const int br0 = (cn + lr) * 128,      br1 = (cn + 32 + lr) * 128;
    const int kof = hi * 16;

    f32x16 acc[2][2];
    #pragma unroll
    for (int mi = 0; mi < 2; mi++)
        #pragma unroll
        for (int ni = 0; ni < 2; ni++)
            #pragma unroll
            for (int r = 0; r < 16; r++) acc[mi][ni][r] = 0.f;

    for (int it = 0; it < CHW / BK; ++it) {
        if (it) __syncthreads();
        #pragma unroll
        for (int j = 0; j < 4; j++) glds16(gA[j] + it * BK, lA[j]);
        #pragma unroll
        for (int j = 0; j < 4; j++) glds16(gB[j] + it * BK, lB[j]);
        __syncthreads();
        #pragma unroll
        for (int ks = 0; ks < 4; ++ks) {
            int off = (ks * 32 + kof) ^ xm;
            f16x8 a0 = *(const f16x8*)(Ab + ar0 + off);
            f16x8 a1 = *(const f16x8*)(Ab + ar1 + off);
            f16x8 b0 = *(const f16x8*)(Bb + br0 + off);
            f16x8 b1 = *(const f16x8*)(Bb + br1 + off);
            acc[0][0] = __builtin_amdgcn_mfma_f32_32x32x16_f16(a0, b0, acc[0][0], 0, 0, 0);
            acc[0][1] = __builtin_amdgcn_mfma_f32_32x32x16_f16(a0, b1, acc[0][1], 0, 0, 0);
            acc[1][0] = __builtin_amdgcn_mfma_f32_32x32x16_f16(a1, b0, acc[1][0], 0, 0, 0);
            acc[1][1] = __builtin_amdgcn_mfma_f32_32x32x16_f16(a1, b1, acc[1][1], 0, 0, 0);
        }
    }

    const float c_cross = sc[2], c_y2 = sc[3];
    #pragma unroll
    for (int mi = 0; mi < 2; mi++)
        #pragma unroll
        for (int ni = 0; ni < 2; ni++) {
            int col = n0 + cn + ni * 32 + lr;
            if (col >= N_IMG) continue;
            float y2v = y2g[col];
            f32x16 v = acc[mi][ni];
            #pragma unroll
            for (int r = 0; r < 16; r++) {
                int row = m0 + rm + mi * 32 + (r & 3) + 8 * (r >> 2) + 4 * hi;
                logits[(size_t)row * N_IMG + col] = c_cross * v[r] - c_y2 * y2v;
            }
        }
}

// ---------------- fused row max + exp + row sum (writes padded eh) ----------------
__global__ void k_softmax(const float* __restrict__ logits, _Float16* __restrict__ eh,
                          float* __restrict__ rowsum) {
    int row = blockIdx.x, tid = threadIdx.x;
    const f32x4* lr = (const f32x4*)(logits + (size_t)row * N_IMG);
    _Float16* erow = eh + (size_t)row * EHS;
    f16x4* er = (f16x4*)erow;
    __shared__ float wred[4];

    if (tid < EHS - N_IMG) erow[N_IMG + tid] = (_Float16)0.f;   // zero K-tail pad

    float m = -3.0e38f;
    for (int i = tid; i < N_IMG / 4; i += 256) {
        f32x4 v = lr[i];
        m = fmaxf(m, fmaxf(fmaxf(v[0], v[1]), fmaxf(v[2], v[3])));
    }
    for (int o = 32; o > 0; o >>= 1) m = fmaxf(m, __shfl_down(m, o));
    if ((tid & 63) == 0) wred[tid >> 6] = m;
    __syncthreads();
    m = fmaxf(fmaxf(wred[0], wred[1]), fmaxf(wred[2], wred[3]));
    __syncthreads();

    float s = 0.f;
    for (int i = tid; i < N_IMG / 4; i += 256) {
        f32x4 v = lr[i];
        float e0 = __expf(v[0] - m), e1 = __expf(v[1] - m);
        float e2 = __expf(v[2] - m), e3 = __expf(v[3] - m);
        s += (e0 + e1) + (e2 + e3);
        f16x4 h;
        h[0] = (_Float16)e0; h[1] = (_Float16)e1;
        h[2] = (_Float16)e2; h[3] = (_Float16)e3;
        er[i] = h;
    }
    for (int o = 32; o > 0; o >>= 1) s += __shfl_down(s, o);
    if ((tid & 63) == 0) wred[tid >> 6] = s;
    __syncthreads();
    if (tid == 0) rowsum[row] = (wred[0] + wred[1]) + (wred[2] + wred[3]);
}

// ---------------- GEMM2: partial[ck] = eh[:,chunk] @ imgh[chunk,:] ----------------
// Fused in-LDS transpose v3: 48 KB LDS -> 3 blk/CU; vectorized transpose
// (8x ds_read_b64 + reg repack + 4x ds_write_b128 per thread per iter).
__global__ __launch_bounds__(256, 3) void k_gemm2(
        const _Float16* __restrict__ eh, const _Float16* __restrict__ imgh,
        float* __restrict__ partial) {
    __shared__ _Float16 Alds[BM * BK];     // 16 KB, swizzled (A = eh)
    __shared__ _Float16 Blds[BN * BK];     // 16 KB, [d][k] swizzled granules
    __shared__ _Float16 Tmp[BK * BN];      // 16 KB, [k][d] linear

    const int tid = threadIdx.x;
    const int wid = tid >> 6, lane = tid & 63;
    const int flat = blockIdx.x;          // 0..767
    const int xcd = flat & 7, loc = flat >> 3;          // loc 0..95
    const int ck  = xcd * 2 + (loc >= 48 ? 1 : 0);
    const int rem = loc - (loc >= 48 ? 48 : 0);         // 0..47
    const int m0 = (rem & 1) * BM;
    const int d0 = (rem >> 1) * BN;
    const int kbase = ck * KCHUNK;

    const _Float16* gA[4]; _Float16* lA[4];
    const _Float16* gB[4]; _Float16* lB[4];
    #pragma unroll
    for (int j = 0; j < 4; j++) {
        int seg = wid * 4 + j;                         // 0..15
        // A: rows seg*8..+8 of eh, swizzled granules
        int row = seg * 8 + (lane >> 3);
        int off = (((lane & 7) ^ (row & 7)) << 3);
        gA[j] = eh + (size_t)(m0 + row) * EHS + kbase + off;
        lA[j] = Alds + seg * 512;
        // B: issue covers 4 imgh k-rows (256B each): lane -> (k-row, 16B granule)
        gB[j] = imgh + (size_t)(kbase + seg * 4 + (lane >> 4)) * CHW + d0 + (lane & 15) * 8;
        lB[j] = Tmp + seg * 512;
    }

    // transpose role: thread -> (d-quad q, k-oct oct)
    const int q   = tid & 31;             // d-quad 0..31 (d = q*4 + dd)
    const int oct = tid >> 5;             // k-octet 0..7

    const int wm = wid >> 1, wn = wid & 1;
    const int rm = wm * 64, cn = wn * 64;
    const int lr = lane & 31, hi = lane >> 5;
    const int xm = (lr & 7) << 4;
    const int ar0 = (rm + lr) * 128, ar1 = (rm + 32 + lr) * 128;
    const int br0 = (cn + lr) * 128, br1 = (cn + 32 + lr) * 128;
    const int kof = hi * 16;

    f32x16 acc[2][2];
    #pragma unroll
    for (int mi = 0; mi < 2; mi++)
        #pragma unroll
        for (int ni = 0; ni < 2; ni++)
            #pragma unroll
            for (int r = 0; r < 16; r++) acc[mi][ni][r] = 0.f;

    for (int it = 0; it < KCHUNK / BK; ++it) {
        __syncthreads();   // prev MFMA reads (Alds,Blds) + prev transpose reads (Tmp) done
        #pragma unroll
        for (int j = 0; j < 4; j++) glds16(gA[j] + it * BK, lA[j]);
        #pragma unroll
        for (int j = 0; j < 4; j++) glds16(gB[j] + (size_t)it * BK * CHW, lB[j]);
        __syncthreads();   // glds landed (vmcnt drained before barrier)

        // transpose Tmp[k][d] -> Blds[d][k] (swizzled): 8 b64 reads, repack, 4 b128 writes
        {
            f16x4 r[8];
            #pragma unroll
            for (int j = 0; j < 8; j++)
                r[j] = *(const f16x4*)&Tmp[(oct * 8 + j) * 128 + q * 4];
            #pragma unroll
            for (int dd = 0; dd < 4; dd++) {
                f16x8 w;
                #pragma unroll
                for (int j = 0; j < 8; j++) w[j] = r[j][dd];
                int d = q * 4 + dd;
                *(f16x8*)((char*)Blds + d * 128 + ((oct ^ (d & 7)) << 4)) = w;
            }
        }
        __syncthreads();   // Blds ready

        const char* Ab = (const char*)Alds;
        const char* Bb = (const char*)Blds;
        #pragma unroll
        for (int ks = 0; ks < 4; ++ks) {
            int off = (ks * 32 + kof) ^ xm;
            f16x8 a0 = *(const f16x8*)(Ab + ar0 + off);
            f16x8 a1 = *(const f16x8*)(Ab + ar1 + off);
            f16x8 b0 = *(const f16x8*)(Bb + br0 + off);
            f16x8 b1 = *(const f16x8*)(Bb + br1 + off);
            acc[0][0] = __builtin_amdgcn_mfma_f32_32x32x16_f16(a0, b0, acc[0][0], 0, 0, 0);
            acc[0][1] = __builtin_amdgcn_mfma_f32_32x32x16_f16(a0, b1, acc[0][1], 0, 0, 0);
            acc[1][0] = __builtin_amdgcn_mfma_f32_32x32x16_f16(a1, b0, acc[1][0], 0, 0, 0);
            acc[1][1] = __builtin_amdgcn_mfma_f32_32x32x16_f16(a1, b1, acc[1][1], 0, 0, 0);
        }
    }

    float* pp = partial + (size_t)ck * BROWS * CHW;
    #pragma unroll
    for (int mi = 0; mi < 2; mi++)
        #pragma unroll
        for (int ni = 0; ni < 2; ni++) {
            int dcol = d0 + cn + ni * 32 + lr;
            f32x16 v = acc[mi][ni];
            #pragma unroll
            for (int r = 0; r < 16; r++) {
                int row = m0 + rm + mi * 32 + (r & 3) + 8 * (r >> 2) + 4 * hi;
                pp[(size_t)row * CHW + dcol] = v[r];
            }
        }
}

// ---------------- reduce partials + final score ----------------
__global__ void k_final(const float* __restrict__ partial, const float* __restrict__ x,
                        const float* __restrict__ rowsum, const float* __restrict__ sc,
                        float* __restrict__ out) {
    int idx = blockIdx.x * 256 + threadIdx.x;
    int row = idx / (CHW / 4);
    float at = sc[0], invbt2 = sc[4];
    float scale = at * invbt2 / rowsum[row];
    const f32x4* p4 = (const f32x4*)partial;
    f32x4 s = p4[idx];
    #pragma unroll
    for (int c = 1; c < NSPLIT; c++) s = s + p4[(size_t)c * (BROWS * CHW / 4) + idx];
    f32x4 xv = ((const f32x4*)x)[idx];
    f32x4 o;
    #pragma unroll
    for (int j = 0; j < 4; j++) o[j] = s[j] * scale - xv[j] * invbt2;
    ((f32x4*)out)[idx] = o;
}

extern "C" void kernel_launch(void* const* d_in, const int* in_sizes, int n_in,
                              void* d_out, int out_size, void* d_ws, size_t ws_size,
                              hipStream_t stream) {
    const float* t   = (const float*)d_in[0];
    const float* x   = (const float*)d_in[1];
    const float* img = (const float*)d_in[2];
    float* out = (float*)d_out;
    char* ws = (char*)d_ws;

    // ws layout (bytes)
    float*    sc     = (float*)(ws + 0);                   // 64 B
    float*    rowsum = (float*)(ws + 256);                 // 1 KB
    float*    y2     = (float*)(ws + 4096);                // 200 KB
    _Float16* xh     = (_Float16*)(ws + 212992);           // 1.5 MB
    _Float16* imgh   = (_Float16*)(ws + 2097152);          // 308.3 MB [NPAD][CHW]
    _Float16* eh     = (_Float16*)(ws + 310378496);        // 25.7 MB  [b][EHS]
    float*    logits = (float*)(ws + 336068608);           // 51.2 MB
    float*    partial = logits;                            // reused (50.4 MB)

    k_scalars<<<1, 64, 0, stream>>>(t, sc);
    k_xprep<<<(BROWS * CHW / 4) / 256, 256, 0, stream>>>(x, xh);
    k_prep<<<NPAD, 256, 0, stream>>>(img, imgh, y2);
    k_gemm1<<<784, 256, 0, stream>>>(xh, imgh, y2, sc, logits);
    k_softmax<<<256, 256, 0, stream>>>(logits, eh, rowsum);
    k_gemm2<<<768, 256, 0, stream>>>(eh, imgh, partial);
    k_final<<<(BROWS * CHW / 4) / 256, 256, 0, stream>>>(partial, x, rowsum, sc, out);
}

// Round 11
// 481.163 us; speedup vs baseline: 1.3463x; 1.0008x over previous
//
#include <hip/hip_runtime.h>

typedef float    f32x4  __attribute__((ext_vector_type(4)));
typedef float    f32x16 __attribute__((ext_vector_type(16)));
typedef _Float16 f16x4  __attribute__((ext_vector_type(4)));
typedef _Float16 f16x8  __attribute__((ext_vector_type(8)));

#define N_IMG 50000
#define NPAD  50176       // imgh padded rows (zeros beyond 50000)
#define BROWS 256
#define CHW   3072
#define BK    64
#define BM    128
#define BN    128
#define EHS   50176       // padded k stride for eh (zeros beyond 50000)
#define KCHUNK 3136       // 49*64 split-K chunk for GEMM2 (16*3136 = 50176)
#define NSPLIT 16

// direct global->LDS (wave-uniform LDS base + lane*16B; per-lane global addr)
__device__ __forceinline__ void glds16(const void* g, void* l) {
    __builtin_amdgcn_global_load_lds(
        (const __attribute__((address_space(1))) void*)g,
        (__attribute__((address_space(3))) void*)l, 16, 0, 0);
}

// ---------------- scalars from t ----------------
__global__ void k_scalars(const float* __restrict__ t, float* __restrict__ sc) {
    if (threadIdx.x == 0) {
        double tv  = (double)t[0];
        double ang = tv * (1.5707963267948966 / 1.008);
        double c   = cos(ang);
        double at  = c;
        double bt2 = 1.0 - c * c;
        sc[0] = (float)at;
        sc[1] = (float)bt2;
        sc[2] = (float)(at / bt2);             // c_cross
        sc[3] = (float)(at * at * 0.5 / bt2);  // c_y2
        sc[4] = (float)(1.0 / bt2);            // inv_bt2
    }
}

// ---------------- x -> f16 ----------------
// -||x||^2 logit term is a per-row constant -> cancelled by row softmax; omitted.
__global__ void k_xprep(const float* __restrict__ x, _Float16* __restrict__ xh) {
    int idx = blockIdx.x * 256 + threadIdx.x;
    f32x4 v = ((const f32x4*)x)[idx];
    f16x4 h;
    h[0] = (_Float16)v[0]; h[1] = (_Float16)v[1];
    h[2] = (_Float16)v[2]; h[3] = (_Float16)v[3];
    ((f16x4*)xh)[idx] = h;
}

// ---------------- img -> f16 [n][d] + y2 (row per block; proven ~150us) ----------
// Rows >= N_IMG written as zeros (NaN-safe padding for GEMM2's K tail).
__global__ void k_prep(const float* __restrict__ img, _Float16* __restrict__ imgh,
                       float* __restrict__ y2) {
    int row = blockIdx.x, tid = threadIdx.x;
    f16x4* dst = (f16x4*)(imgh + (size_t)row * CHW);
    if (row >= N_IMG) {
        f16x4 z = {(_Float16)0.f, (_Float16)0.f, (_Float16)0.f, (_Float16)0.f};
        #pragma unroll
        for (int i = 0; i < 3; i++) dst[tid + i * 256] = z;
        return;
    }
    const f32x4* src = (const f32x4*)(img + (size_t)row * CHW);
    float s = 0.f;
    #pragma unroll
    for (int i = 0; i < 3; i++) {
        f32x4 v = src[tid + i * 256];
        s += v[0]*v[0] + v[1]*v[1] + v[2]*v[2] + v[3]*v[3];
        f16x4 h;
        h[0] = (_Float16)v[0]; h[1] = (_Float16)v[1];
        h[2] = (_Float16)v[2]; h[3] = (_Float16)v[3];
        dst[tid + i * 256] = h;
    }
    for (int o = 32; o > 0; o >>= 1) s += __shfl_down(s, o);
    __shared__ float wsum[4];
    if ((tid & 63) == 0) wsum[tid >> 6] = s;
    __syncthreads();
    if (tid == 0) y2[row] = (wsum[0] + wsum[1]) + (wsum[2] + wsum[3]);
}

// ---------------- GEMM1: logits = c_cross*(xh@imghT) - c_y2*y2 ----------------
// m97 structure (proven R4/R6/R8/R9/R10) + XCD-aware flat decode (784 = 8 x 98).
__global__ __launch_bounds__(256, 3) void k_gemm1(
        const _Float16* __restrict__ xh, const _Float16* __restrict__ imgh,
        const float* __restrict__ y2g, const float* __restrict__ sc,
        float* __restrict__ logits) {
    __shared__ _Float16 Alds[BM * BK];   // 16 KB, [row][g^(row&7)] 16B granules
    __shared__ _Float16 Blds[BN * BK];   // 16 KB

    const int tid = threadIdx.x;
    const int wid = tid >> 6, lane = tid & 63;
    const int flat = blockIdx.x;          // 0..783
    const int xcd = flat & 7, loc = flat >> 3;          // loc 0..97
    const int m0 = (loc & 1) * BM;
    const int n0 = (xcd * 49 + (loc >> 1)) * BN;

    const _Float16* gA[4]; const _Float16* gB[4];
    _Float16* lA[4]; _Float16* lB[4];
    #pragma unroll
    for (int j = 0; j < 4; j++) {
        int seg = wid * 4 + j;
        int row = seg * 8 + (lane >> 3);
        int off = (((lane & 7) ^ (row & 7)) << 3);   // f16 elements
        gA[j] = xh + (size_t)(m0 + row) * CHW + off;
        int rb = n0 + row; if (rb > N_IMG - 1) rb = N_IMG - 1;
        gB[j] = imgh + (size_t)rb * CHW + off;
        lA[j] = Alds + seg * 512;
        lB[j] = Blds + seg * 512;
    }

    const int wm = wid >> 1, wn = wid & 1;
    const int rm = wm * 64, cn = wn * 64;
    const int lr = lane & 31, hi = lane >> 5;
    const int xm = (lr & 7) << 4;                    // read-side byte XOR
    const char* Ab = (const char*)Alds;
    const char* Bb = (const char*)Blds;
    const int ar0 = (rm + lr) * 128,      ar1 = (rm + 32 + lr) * 128;
    const int br0 = (cn + lr) * 128,      br1 = (cn + 32 + lr) * 128;
    const int kof = hi * 16;

    f32x16 acc[2][2];
    #pragma unroll
    for (int mi = 0; mi < 2; mi++)
        #pragma unroll
        for (int ni = 0; ni < 2; ni++)
            #pragma unroll
            for (int r = 0; r < 16; r++) acc[mi][ni][r] = 0.f;

    for (int it = 0; it < CHW / BK; ++it) {
        if (it) __syncthreads();
        #pragma unroll
        for (int j = 0; j < 4; j++) glds16(gA[j] + it * BK, lA[j]);
        #pragma unroll
        for (int j = 0; j < 4; j++) glds16(gB[j] + it * BK, lB[j]);
        __syncthreads();
        #pragma unroll
        for (int ks = 0; ks < 4; ++ks) {
            int off = (ks * 32 + kof) ^ xm;
            f16x8 a0 = *(const f16x8*)(Ab + ar0 + off);
            f16x8 a1 = *(const f16x8*)(Ab + ar1 + off);
            f16x8 b0 = *(const f16x8*)(Bb + br0 + off);
            f16x8 b1 = *(const f16x8*)(Bb + br1 + off);
            acc[0][0] = __builtin_amdgcn_mfma_f32_32x32x16_f16(a0, b0, acc[0][0], 0, 0, 0);
            acc[0][1] = __builtin_amdgcn_mfma_f32_32x32x16_f16(a0, b1, acc[0][1], 0, 0, 0);
            acc[1][0] = __builtin_amdgcn_mfma_f32_32x32x16_f16(a1, b0, acc[1][0], 0, 0, 0);
            acc[1][1] = __builtin_amdgcn_mfma_f32_32x32x16_f16(a1, b1, acc[1][1], 0, 0, 0);
        }
    }

    const float c_cross = sc[2], c_y2 = sc[3];
    #pragma unroll
    for (int mi = 0; mi < 2; mi++)
        #pragma unroll
        for (int ni = 0; ni < 2; ni++) {
            int col = n0 + cn + ni * 32 + lr;
            if (col >= N_IMG) continue;
            float y2v = y2g[col];
            f32x16 v = acc[mi][ni];
            #pragma unroll
            for (int r = 0; r < 16; r++) {
                int row = m0 + rm + mi * 32 + (r & 3) + 8 * (r >> 2) + 4 * hi;
                logits[(size_t)row * N_IMG + col] = c_cross * v[r] - c_y2 * y2v;
            }
        }
}

// ---------------- fused row max + exp + row sum (writes padded eh) ----------------
__global__ void k_softmax(const float* __restrict__ logits, _Float16* __restrict__ eh,
                          float* __restrict__ rowsum) {
    int row = blockIdx.x, tid = threadIdx.x;
    const f32x4* lr = (const f32x4*)(logits + (size_t)row * N_IMG);
    _Float16* erow = eh + (size_t)row * EHS;
    f16x4* er = (f16x4*)erow;
    __shared__ float wred[4];

    if (tid < EHS - N_IMG) erow[N_IMG + tid] = (_Float16)0.f;   // zero K-tail pad

    float m = -3.0e38f;
    for (int i = tid; i < N_IMG / 4; i += 256) {
        f32x4 v = lr[i];
        m = fmaxf(m, fmaxf(fmaxf(v[0], v[1]), fmaxf(v[2], v[3])));
    }
    for (int o = 32; o > 0; o >>= 1) m = fmaxf(m, __shfl_down(m, o));
    if ((tid & 63) == 0) wred[tid >> 6] = m;
    __syncthreads();
    m = fmaxf(fmaxf(wred[0], wred[1]), fmaxf(wred[2], wred[3]));
    __syncthreads();

    float s = 0.f;
    for (int i = tid; i < N_IMG / 4; i += 256) {
        f32x4 v = lr[i];
        float e0 = __expf(v[0] - m), e1 = __expf(v[1] - m);
        float e2 = __expf(v[2] - m), e3 = __expf(v[3] - m);
        s += (e0 + e1) + (e2 + e3);
        f16x4 h;
        h[0] = (_Float16)e0; h[1] = (_Float16)e1;
        h[2] = (_Float16)e2; h[3] = (_Float16)e3;
        er[i] = h;
    }
    for (int o = 32; o > 0; o >>= 1) s += __shfl_down(s, o);
    if ((tid & 63) == 0) wred[tid >> 6] = s;
    __syncthreads();
    if (tid == 0) rowsum[row] = (wred[0] + wred[1]) + (wred[2] + wred[3]);
}

// ---------------- GEMM2: partial[ck] = eh[:,chunk] @ imgh[chunk,:] ----------------
// Fused in-LDS transpose v4: 2-barrier schedule. P1: A-frags->regs + transpose
// Tmp->Blds. P2: glds(it+1) overlapped with MFMA (A from regs, B from Blds).
__global__ __launch_bounds__(256, 3) void k_gemm2(
        const _Float16* __restrict__ eh, const _Float16* __restrict__ imgh,
        float* __restrict__ partial) {
    __shared__ _Float16 Alds[BM * BK];     // 16 KB, swizzled (A = eh)
    __shared__ _Float16 Blds[BN * BK];     // 16 KB, [d][k] swizzled granules
    __shared__ _Float16 Tmp[BK * BN];      // 16 KB, [k][d] linear

    const int tid = threadIdx.x;
    const int wid = tid >> 6, lane = tid & 63;
    const int flat = blockIdx.x;          // 0..767
    const int xcd = flat & 7, loc = flat >> 3;          // loc 0..95
    const int ck  = xcd * 2 + (loc >= 48 ? 1 : 0);
    const int rem = loc - (loc >= 48 ? 48 : 0);         // 0..47
    const int m0 = (rem & 1) * BM;
    const int d0 = (rem >> 1) * BN;
    const int kbase = ck * KCHUNK;

    const _Float16* gA[4]; _Float16* lA[4];
    const _Float16* gB[4]; _Float16* lB[4];
    #pragma unroll
    for (int j = 0; j < 4; j++) {
        int seg = wid * 4 + j;                         // 0..15
        // A: rows seg*8..+8 of eh, swizzled granules
        int row = seg * 8 + (lane >> 3);
        int off = (((lane & 7) ^ (row & 7)) << 3);
        gA[j] = eh + (size_t)(m0 + row) * EHS + kbase + off;
        lA[j] = Alds + seg * 512;
        // B: issue covers 4 imgh k-rows (256B each): lane -> (k-row, 16B granule)
        gB[j] = imgh + (size_t)(kbase + seg * 4 + (lane >> 4)) * CHW + d0 + (lane & 15) * 8;
        lB[j] = Tmp + seg * 512;
    }

    // transpose role: thread -> (d-quad q, k-oct oct)
    const int q   = tid & 31;             // d-quad 0..31 (d = q*4 + dd)
    const int oct = tid >> 5;             // k-octet 0..7

    const int wm = wid >> 1, wn = wid & 1;
    const int rm = wm * 64, cn = wn * 64;
    const int lr = lane & 31, hi = lane >> 5;
    const int xm = (lr & 7) << 4;
    const int ar0 = (rm + lr) * 128, ar1 = (rm + 32 + lr) * 128;
    const int br0 = (cn + lr) * 128, br1 = (cn + 32 + lr) * 128;
    const int kof = hi * 16;
    const char* Ab = (const char*)Alds;
    const char* Bb = (const char*)Blds;

    f32x16 acc[2][2];
    #pragma unroll
    for (int mi = 0; mi < 2; mi++)
        #pragma unroll
        for (int ni = 0; ni < 2; ni++)
            #pragma unroll
            for (int r = 0; r < 16; r++) acc[mi][ni][r] = 0.f;

    // prologue: stage it=0
    #pragma unroll
    for (int j = 0; j < 4; j++) glds16(gA[j], lA[j]);
    #pragma unroll
    for (int j = 0; j < 4; j++) glds16(gB[j], lB[j]);

    f16x8 afr0[4], afr1[4];   // A fragments for current iter (32 VGPR)

    for (int it = 0; it < KCHUNK / BK; ++it) {
        __syncthreads();   // glds(it) drained; MFMA(it-1) Blds reads done

        // P1: A fragments -> registers, then transpose Tmp[k][d] -> Blds[d][k]
        #pragma unroll
        for (int ks = 0; ks < 4; ++ks) {
            int offa = (ks * 32 + kof) ^ xm;
            afr0[ks] = *(const f16x8*)(Ab + ar0 + offa);
            afr1[ks] = *(const f16x8*)(Ab + ar1 + offa);
        }
        {
            f16x4 r[8];
            #pragma unroll
            for (int j = 0; j < 8; j++)
                r[j] = *(const f16x4*)&Tmp[(oct * 8 + j) * 128 + q * 4];
            #pragma unroll
            for (int dd = 0; dd < 4; dd++) {
                f16x8 w;
                #pragma unroll
                for (int j = 0; j < 8; j++) w[j] = r[j][dd];
                int d = q * 4 + dd;
                *(f16x8*)((char*)Blds + d * 128 + ((oct ^ (d & 7)) << 4)) = w;
            }
        }
        __syncthreads();   // Blds ready; Alds/Tmp free for prefetch

        // P2: prefetch it+1 (overlaps MFMA below; drained at next loop-top barrier)
        if (it + 1 < KCHUNK / BK) {
            #pragma unroll
            for (int j = 0; j < 4; j++) glds16(gA[j] + (it + 1) * BK, lA[j]);
            #pragma unroll
            for (int j = 0; j < 4; j++) glds16(gB[j] + (size_t)(it + 1) * BK * CHW, lB[j]);
        }
        #pragma unroll
        for (int ks = 0; ks < 4; ++ks) {
            int offb = (ks * 32 + kof) ^ xm;
            f16x8 b0 = *(const f16x8*)(Bb + br0 + offb);
            f16x8 b1 = *(const f16x8*)(Bb + br1 + offb);
            acc[0][0] = __builtin_amdgcn_mfma_f32_32x32x16_f16(afr0[ks], b0, acc[0][0], 0, 0, 0);
            acc[0][1] = __builtin_amdgcn_mfma_f32_32x32x16_f16(afr0[ks], b1, acc[0][1], 0, 0, 0);
            acc[1][0] = __builtin_amdgcn_mfma_f32_32x32x16_f16(afr1[ks], b0, acc[1][0], 0, 0, 0);
            acc[1][1] = __builtin_amdgcn_mfma_f32_32x32x16_f16(afr1[ks], b1, acc[1][1], 0, 0, 0);
        }
    }

    float* pp = partial + (size_t)ck * BROWS * CHW;
    #pragma unroll
    for (int mi = 0; mi < 2; mi++)
        #pragma unroll
        for (int ni = 0; ni < 2; ni++) {
            int dcol = d0 + cn + ni * 32 + lr;
            f32x16 v = acc[mi][ni];
            #pragma unroll
            for (int r = 0; r < 16; r++) {
                int row = m0 + rm + mi * 32 + (r & 3) + 8 * (r >> 2) + 4 * hi;
                pp[(size_t)row * CHW + dcol] = v[r];
            }
        }
}

// ---------------- reduce partials + final score ----------------
__global__ void k_final(const float* __restrict__ partial, const float* __restrict__ x,
                        const float* __restrict__ rowsum, const float* __restrict__ sc,
                        float* __restrict__ out) {
    int idx = blockIdx.x * 256 + threadIdx.x;
    int row = idx / (CHW / 4);
    float at = sc[0], invbt2 = sc[4];
    float scale = at * invbt2 / rowsum[row];
    const f32x4* p4 = (const f32x4*)partial;
    f32x4 s = p4[idx];
    #pragma unroll
    for (int c = 1; c < NSPLIT; c++) s = s + p4[(size_t)c * (BROWS * CHW / 4) + idx];
    f32x4 xv = ((const f32x4*)x)[idx];
    f32x4 o;
    #pragma unroll
    for (int j = 0; j < 4; j++) o[j] = s[j] * scale - xv[j] * invbt2;
    ((f32x4*)out)[idx] = o;
}

extern "C" void kernel_launch(void* const* d_in, const int* in_sizes, int n_in,
                              void* d_out, int out_size, void* d_ws, size_t ws_size,
                              hipStream_t stream) {
    const float* t   = (const float*)d_in[0];
    const float* x   = (const float*)d_in[1];
    const float* img = (const float*)d_in[2];
    float* out = (float*)d_out;
    char* ws = (char*)d_ws;

    // ws layout (bytes)
    float*    sc     = (float*)(ws + 0);                   // 64 B
    float*    rowsum = (float*)(ws + 256);                 // 1 KB
    float*    y2     = (float*)(ws + 4096);                // 200 KB
    _Float16* xh     = (_Float16*)(ws + 212992);           // 1.5 MB
    _Float16* imgh   = (_Float16*)(ws + 2097152);          // 308.3 MB [NPAD][CHW]
    _Float16* eh     = (_Float16*)(ws + 310378496);        // 25.7 MB  [b][EHS]
    float*    logits = (float*)(ws + 336068608);           // 51.2 MB
    float*    partial = logits;                            // reused (50.4 MB)

    k_scalars<<<1, 64, 0, stream>>>(t, sc);
    k_xprep<<<(BROWS * CHW / 4) / 256, 256, 0, stream>>>(x, xh);
    k_prep<<<NPAD, 256, 0, stream>>>(img, imgh, y2);
    k_gemm1<<<784, 256, 0, stream>>>(xh, imgh, y2, sc, logits);
    k_softmax<<<256, 256, 0, stream>>>(logits, eh, rowsum);
    k_gemm2<<<768, 256, 0, stream>>>(eh, imgh, partial);
    k_final<<<(BROWS * CHW / 4) / 256, 256, 0, stream>>>(partial, x, rowsum, sc, out);
}